// Round 5
// baseline (62.000 us; speedup 1.0000x reference)
//
#include <hip/hip_runtime.h>
#include <cstdint>

#define DEVFN __device__ __forceinline__

struct U128 { unsigned long long lo, hi; };

// rotate right by s (1..127)
DEVFN U128 rotr128(U128 w, int s) {
    U128 r;
    if (s == 64) { r.lo = w.hi; r.hi = w.lo; return r; }
    if (s < 64) {
        r.lo = (w.lo >> s) | (w.hi << (64 - s));
        r.hi = (w.hi >> s) | (w.lo << (64 - s));
    } else {
        int t = s - 64;
        unsigned long long lo = w.hi, hi = w.lo;
        r.lo = (lo >> t) | (hi << (64 - t));
        r.hi = (hi >> t) | (lo << (64 - t));
    }
    return r;
}

// logical shift right by s (1..127)
DEVFN U128 shr128(U128 w, int s) {
    U128 r;
    if (s == 64) { r.lo = w.hi; r.hi = 0ull; return r; }
    if (s < 64) {
        r.lo = (w.lo >> s) | (w.hi << (64 - s));
        r.hi = w.hi >> s;
    } else {
        r.lo = w.hi >> (s - 64); r.hi = 0ull;
    }
    return r;
}

// chunk = 16 rows. fcum(L) = sum_{l=1..L} ceil(l/16); total tasks = fcum(128) = 576
DEVFN int fcum16(int L) { int q = L >> 4, s = L & 15; return 8 * q * (q + 1) + s * (q + 1); }
DEVFN int tstart(int r) { return 576 - fcum16(128 - r); }

// K1: W0 reduction into 576 task rows (contiguous reads, balanced) + S (block 576)
__global__ __launch_bounds__(256) void k1_reduce(const int* __restrict__ x,
                                                 const int* __restrict__ masks,
                                                 const float* __restrict__ W0,
                                                 float* __restrict__ S,
                                                 float* __restrict__ A2,
                                                 float* __restrict__ G2) {
    int bid = blockIdx.x;
    int tid = threadIdx.x;

    if (bid == 576) {
        int b = tid >> 2;        // 64 rows of x
        int rc = tid & 3;        // 4 chunks of 32 r
        const int* xb = x + b * 128;
        U128 w; w.lo = 0ull; w.hi = 0ull;
        #pragma unroll
        for (int p = 0; p < 64; ++p) w.lo |= (unsigned long long)(xb[p] & 1) << p;
        #pragma unroll
        for (int p = 0; p < 64; ++p) w.hi |= (unsigned long long)(xb[64 + p] & 1) << p;
        int r0 = rc * 32;
        if (r0 & 32) { U128 tt = rotr128(w, 32); w.lo ^= tt.lo; w.hi ^= tt.hi; }
        if (r0 & 64) { U128 tt = rotr128(w, 64); w.lo ^= tt.lo; w.hi ^= tt.hi; }
        for (int rr = 0; rr < 32; ++rr) {
            int r = r0 + rr;
            int pc = __popcll(w.lo) + __popcll(w.hi);
            int sv = (r == 0) ? pc : (128 - pc);
            S[b * 128 + r] = (float)(2 * sv);
            U128 tt = rotr128(w, 1);
            w.lo ^= tt.lo; w.hi ^= tt.hi;
        }
        return;
    }

    // decode task -> (r, chunk c)
    int lo = 0, hi = 127;
    while (lo < hi) { int mid = (lo + hi + 1) >> 1; if (tstart(mid) <= bid) lo = mid; else hi = mid - 1; }
    int r = lo;
    int c = bid - tstart(r);
    int j0 = c * 16;
    int L = 128 - r - j0; if (L > 16) L = 16;

    __shared__ unsigned long long mw[3][2];
    __shared__ float cA[16], cG[16];

    if (tid < 128) {
        int half = tid >> 6, lane = tid & 63;
        #pragma unroll
        for (int k = 0; k < 3; ++k) {
            unsigned long long bal = __ballot(masks[k * 128 + half * 64 + lane] & 1);
            if (lane == 0) mw[k][half] = bal;
        }
    }
    __syncthreads();
    if (tid < 16) {
        int j = j0 + tid;
        int cc = 0;
        #pragma unroll
        for (int k = 0; k < 3; ++k) {
            U128 m; m.lo = mw[k][0]; m.hi = mw[k][1];
            #pragma unroll
            for (int s = 1; s <= 64; s <<= 1) {
                if (r & s) { U128 tt = shr128(m, s); m.lo ^= tt.lo; m.hi ^= tt.hi; }
            }
            int bit = (j < 64) ? (int)((m.lo >> j) & 1) : (int)((m.hi >> (j - 64)) & 1);
            cc += bit;
        }
        cA[tid] = 0.5f * (float)cc - 1.0f;
        cG[tid] = (float)(2 - cc) * (1.0f / 256.0f);
    }
    __syncthreads();

    int rowoff = r * 128 - (r * (r - 1)) / 2 + j0;
    const float4* p = (const float4*)(W0 + (size_t)rowoff * 1024) + tid;
    float4 aA = {0.f, 0.f, 0.f, 0.f}, aG = {0.f, 0.f, 0.f, 0.f};
    #pragma unroll 8
    for (int jj = 0; jj < L; ++jj) {
        float4 v = p[jj * 256];
        float ca = cA[jj], cg = cG[jj];
        aA.x += ca * v.x; aA.y += ca * v.y; aA.z += ca * v.z; aA.w += ca * v.w;
        aG.x += cg * v.x; aG.y += cg * v.y; aG.z += cg * v.z; aG.w += cg * v.w;
    }
    ((float4*)(A2 + (size_t)bid * 1024))[tid] = aA;
    ((float4*)(G2 + (size_t)bid * 1024))[tid] = aG;
}

// K2: h0[b][h] = relu(b0[h] + sum_rows (A2[row][h] + S[b][rtab[row]]*G2[row][h]))
//     also: z1[b][h] = b1[h]  (init for K3's atomic accumulation)
// grid: (64 h-groups of 16) x (4 b-tiles of 16); thread = (h, b)
__global__ __launch_bounds__(256) void k2_h0(const float* __restrict__ A2,
                                             const float* __restrict__ G2,
                                             const float* __restrict__ S,
                                             const float* __restrict__ b0,
                                             const float* __restrict__ b1,
                                             float* __restrict__ h0,
                                             float* __restrict__ z1) {
    int hg = blockIdx.x;          // 0..63
    int bt = blockIdx.y;          // 0..3
    int tid = threadIdx.x;
    int hl = tid & 15, bl = tid >> 4;
    int h = hg * 16 + hl;
    int b = bt * 16 + bl;

    __shared__ float Sblk[16][128];
    __shared__ short rtab[576];

    #pragma unroll
    for (int i = 0; i < 8; ++i) {
        int idx = tid + i * 256;
        int bb = idx >> 7, rr = idx & 127;
        Sblk[bb][rr] = S[(bt * 16 + bb) * 128 + rr];
    }
    if (tid < 128) {
        int r = tid;
        int s0 = tstart(r);
        int n = (128 - r + 15) >> 4;
        for (int c = 0; c < n; ++c) rtab[s0 + c] = (short)r;
    }
    __syncthreads();

    float acc = b0[h];
    #pragma unroll 8
    for (int row = 0; row < 576; ++row) {
        float a = A2[row * 1024 + h];
        float g = G2[row * 1024 + h];
        acc += a + Sblk[bl][rtab[row]] * g;
    }
    h0[b * 1024 + h] = fmaxf(acc, 0.f);
    z1[b * 1024 + h] = b1[h];
}

// K3: split-K layer-2, atomically accumulated into z1 (pre-initialized with b1)
__global__ __launch_bounds__(256) void k3_layer2(const float* __restrict__ h0,
                                                 const float* __restrict__ W1,
                                                 float* __restrict__ z1) {
    int hc = blockIdx.x;           // 16 (64 h each)
    int kc = blockIdx.y;           // 16 (64 k each)
    int tid = threadIdx.x;
    __shared__ float Wt[64][64];   // [k][h]
    __shared__ float Ht[64][64];   // [b][k]
    #pragma unroll
    for (int i = 0; i < 16; ++i) {
        int idx = tid + i * 256;
        int a = idx >> 6, c = idx & 63;
        Wt[a][c] = W1[(kc * 64 + a) * 1024 + hc * 64 + c];
        Ht[a][c] = h0[a * 1024 + kc * 64 + c];
    }
    __syncthreads();
    int h = tid & 63, bg = tid >> 6;    // 4 b-groups x 16 b
    float acc[16];
    #pragma unroll
    for (int i = 0; i < 16; ++i) acc[i] = 0.f;
    for (int k = 0; k < 64; k += 4) {
        float w0_ = Wt[k][h], w1_ = Wt[k + 1][h], w2_ = Wt[k + 2][h], w3_ = Wt[k + 3][h];
        #pragma unroll
        for (int bb = 0; bb < 16; ++bb) {
            float4 hv = *(const float4*)&Ht[bg * 16 + bb][k];
            acc[bb] += hv.x * w0_ + hv.y * w1_ + hv.z * w2_ + hv.w * w3_;
        }
    }
    #pragma unroll
    for (int bb = 0; bb < 16; ++bb) {
        int b = bg * 16 + bb;
        unsafeAtomicAdd(&z1[b * 1024 + hc * 64 + h], acc[bb]);
    }
}

// K4: out[b] = sum_h relu(z1[b][h]) * Wo[h] + bo
__global__ __launch_bounds__(256) void k4_out(const float* __restrict__ z1,
                                              const float* __restrict__ Wo,
                                              const float* __restrict__ bo,
                                              float* __restrict__ out) {
    int b = blockIdx.x;
    int tid = threadIdx.x;
    float acc = 0.f;
    #pragma unroll
    for (int i = 0; i < 4; ++i) {
        int h = tid + i * 256;
        acc += fmaxf(z1[b * 1024 + h], 0.f) * Wo[h];
    }
    #pragma unroll
    for (int off = 32; off >= 1; off >>= 1) acc += __shfl_down(acc, off);
    __shared__ float red[4];
    if ((tid & 63) == 0) red[tid >> 6] = acc;
    __syncthreads();
    if (tid == 0) out[b] = red[0] + red[1] + red[2] + red[3] + bo[0];
}

extern "C" void kernel_launch(void* const* d_in, const int* in_sizes, int n_in,
                              void* d_out, int out_size, void* d_ws, size_t ws_size,
                              hipStream_t stream) {
    const int*   x     = (const int*)d_in[0];    // (64,128) 0/1
    const int*   masks = (const int*)d_in[1];    // (3,128) 0/1
    const float* W0    = (const float*)d_in[2];  // (8256,1024)
    const float* b0    = (const float*)d_in[3];  // (1024)
    const float* W1    = (const float*)d_in[4];  // (1024,1024)
    const float* b1    = (const float*)d_in[5];  // (1024)
    const float* Wo    = (const float*)d_in[6];  // (1024,1)
    const float* bo    = (const float*)d_in[7];  // (1)
    float* out = (float*)d_out;                  // (64,1)

    char* ws = (char*)d_ws;
    float* S  = (float*)(ws);                          // 64*128*4     = 32 KB
    float* A2 = (float*)(ws + (32u   << 10));          // 576*1024*4   = 2304 KB
    float* G2 = (float*)(ws + (2336u << 10));          // 576*1024*4   = 2304 KB
    float* h0 = (float*)(ws + (4640u << 10));          // 64*1024*4    = 256 KB
    float* z1 = (float*)(ws + (4896u << 10));          // 64*1024*4    = 256 KB

    k1_reduce<<<577, 256, 0, stream>>>(x, masks, W0, S, A2, G2);
    k2_h0<<<dim3(64, 4), 256, 0, stream>>>(A2, G2, S, b0, b1, h0, z1);
    k3_layer2<<<dim3(16, 16), 256, 0, stream>>>(h0, W1, z1);
    k4_out<<<64, 256, 0, stream>>>(z1, Wo, bo, out);
}

// Round 6
// 50.505 us; speedup vs baseline: 1.2276x; 1.2276x over previous
//
#include <hip/hip_runtime.h>
#include <cstdint>

#define DEVFN __device__ __forceinline__

struct U128 { unsigned long long lo, hi; };

// rotate right by s (1..127): bit q of result = bit (q+s)%128 of w
DEVFN U128 rotr128(U128 w, int s) {
    U128 r;
    if (s == 64) { r.lo = w.hi; r.hi = w.lo; return r; }
    if (s < 64) {
        r.lo = (w.lo >> s) | (w.hi << (64 - s));
        r.hi = (w.hi >> s) | (w.lo << (64 - s));
    } else {
        int t = s - 64;
        unsigned long long lo = w.hi, hi = w.lo;
        r.lo = (lo >> t) | (hi << (64 - t));
        r.hi = (hi >> t) | (lo << (64 - t));
    }
    return r;
}

// logical shift right by s (1..127)
DEVFN U128 shr128(U128 w, int s) {
    U128 r;
    if (s == 64) { r.lo = w.hi; r.hi = 0ull; return r; }
    if (s < 64) {
        r.lo = (w.lo >> s) | (w.hi << (64 - s));
        r.hi = w.hi >> s;
    } else {
        r.lo = w.hi >> (s - 64); r.hi = 0ull;
    }
    return r;
}

// KB: fused {S computation (block 768)} + {balanced W0 reduction (blocks 0..767)}
// (identical to the 39 µs round-2 kernel)
__global__ __launch_bounds__(256) void kB(const int* __restrict__ x,
                                          const int* __restrict__ masks,
                                          const float* __restrict__ W0,
                                          float* __restrict__ S,
                                          float* __restrict__ A2,
                                          float* __restrict__ G2) {
    int bid = blockIdx.x;
    int tid = threadIdx.x;

    if (bid == 768) {
        int b = tid >> 2;        // 64 rows of x
        int rc = tid & 3;        // 4 chunks of 32 r's
        const int* xb = x + b * 128;
        U128 w; w.lo = 0ull; w.hi = 0ull;
        #pragma unroll
        for (int p = 0; p < 64; ++p) w.lo |= (unsigned long long)(xb[p] & 1) << p;
        #pragma unroll
        for (int p = 0; p < 64; ++p) w.hi |= (unsigned long long)(xb[64 + p] & 1) << p;
        int r0 = rc * 32;
        if (r0 & 32) { U128 t = rotr128(w, 32); w.lo ^= t.lo; w.hi ^= t.hi; }
        if (r0 & 64) { U128 t = rotr128(w, 64); w.lo ^= t.lo; w.hi ^= t.hi; }
        for (int rr = 0; rr < 32; ++rr) {
            int r = r0 + rr;
            int pc = __popcll(w.lo) + __popcll(w.hi);
            int sv = (r == 0) ? pc : (128 - pc);
            S[b * 128 + r] = (float)(2 * sv);
            U128 t = rotr128(w, 1);
            w.lo ^= t.lo; w.hi ^= t.hi;
        }
        return;
    }

    int hc = bid & 3;            // 4 chunks of 256 h
    int y  = bid >> 2;           // 0..191 (r, segment) task
    int r, jstart, jend, slice;
    if (y < 128) { r = y >> 1; slice = y & 1; jstart = slice * 64; jend = (slice == 0) ? 64 : (128 - r); }
    else         { r = y - 64;  slice = 0;    jstart = 0;          jend = 128 - r; }

    int h = hc * 256 + tid;

    __shared__ unsigned long long mw[3][2];
    __shared__ float cA[64], cG[64];

    if (tid < 128) {
        int half = tid >> 6;
        int lane = tid & 63;
        #pragma unroll
        for (int k = 0; k < 3; ++k) {
            unsigned long long bal = __ballot(masks[k * 128 + half * 64 + lane] & 1);
            if (lane == 0) mw[k][half] = bal;
        }
    }
    __syncthreads();
    if (tid < 64) {
        int j = jstart + tid;
        int c = 0;
        #pragma unroll
        for (int k = 0; k < 3; ++k) {
            U128 m; m.lo = mw[k][0]; m.hi = mw[k][1];
            #pragma unroll
            for (int s = 1; s <= 64; s <<= 1) {
                if (r & s) { U128 t = shr128(m, s); m.lo ^= t.lo; m.hi ^= t.hi; }
            }
            int bit = (j < 64) ? (int)((m.lo >> j) & 1) : (int)((m.hi >> (j - 64)) & 1);
            c += bit;
        }
        cA[tid] = 0.5f * (float)c - 1.0f;
        cG[tid] = (float)(2 - c) * (1.0f / 256.0f);
    }
    __syncthreads();

    int off = r * 128 - (r * (r - 1)) / 2;
    const float* p = W0 + (off + jstart) * 1024 + h;
    int L = jend - jstart;
    float accA = 0.f, accG = 0.f;
    #pragma unroll 8
    for (int j = 0; j < L; ++j) {
        float w = p[j * 1024];
        accA += cA[j] * w;
        accG += cG[j] * w;
    }
    int row = slice * 128 + r;
    A2[row * 1024 + h] = accA;
    G2[row * 1024 + h] = accG;
}

// KC': low-traffic layer-1 assembly.
// h0[b][h] = relu(b0[h] + sum_row A2[row][h] + sum_row S[b][r(row)]*G2[row][h]),
// r(row) = row & 127 (rows 0..127: slice0 r=row; rows 128..191: slice1 r=row-128).
// grid (16 hc, 4 bt); thread = (bg = tid>>6 in 0..3, hl = tid&63); 4 b per thread.
__global__ __launch_bounds__(256) void kC(const float* __restrict__ A2,
                                          const float* __restrict__ G2,
                                          const float* __restrict__ S,
                                          const float* __restrict__ b0,
                                          float* __restrict__ h0) {
    int hc = blockIdx.x;          // 0..15
    int bt = blockIdx.y;          // 0..3
    int tid = threadIdx.x;
    int hl = tid & 63, bg = tid >> 6;      // wave w <-> bg w (uniform per wave)
    int h = hc * 64 + hl;

    __shared__ float Ssh[128][16];         // [r][b-local] -> wave-uniform broadcast reads
    #pragma unroll
    for (int i = 0; i < 8; ++i) {
        int idx = tid + i * 256;           // 0..2047
        int r = idx >> 4, bl = idx & 15;
        Ssh[r][bl] = S[(bt * 16 + bl) * 128 + r];
    }
    __syncthreads();

    float accA = 0.f;
    float acc[4] = {0.f, 0.f, 0.f, 0.f};
    #pragma unroll 4
    for (int row = 0; row < 192; ++row) {
        int r = row & 127;
        float a = A2[row * 1024 + h];
        float g = G2[row * 1024 + h];
        accA += a;
        #pragma unroll
        for (int bb = 0; bb < 4; ++bb) {
            acc[bb] += Ssh[r][bg * 4 + bb] * g;   // wave-uniform LDS address
        }
    }
    float base = b0[h] + accA;
    #pragma unroll
    for (int bb = 0; bb < 4; ++bb) {
        int b = bt * 16 + bg * 4 + bb;
        h0[b * 1024 + h] = fmaxf(base + acc[bb], 0.f);
    }
}

// KD: split-K GEMM partials: z1part[kc][b][h] = sum_{k in chunk} h0[b][k] * W1[k][h]
__global__ __launch_bounds__(256) void kD(const float* __restrict__ h0,
                                          const float* __restrict__ W1,
                                          float* __restrict__ z1part) {
    int hc = blockIdx.x;           // 16 (64 h each)
    int kc = blockIdx.y;           // 16 (64 k each)
    int tid = threadIdx.x;
    __shared__ float Wt[64][64];   // [k][h]
    __shared__ float Ht[64][64];   // [b][k]
    #pragma unroll
    for (int i = 0; i < 16; ++i) {
        int idx = tid + i * 256;
        int a = idx >> 6, c = idx & 63;
        Wt[a][c] = W1[(kc * 64 + a) * 1024 + hc * 64 + c];
        Ht[a][c] = h0[a * 1024 + kc * 64 + c];
    }
    __syncthreads();
    int h = tid & 63, bg = tid >> 6;    // 4 b-groups x 16 b
    float acc[16];
    #pragma unroll
    for (int i = 0; i < 16; ++i) acc[i] = 0.f;
    for (int k = 0; k < 64; k += 4) {
        float w0_ = Wt[k][h], w1_ = Wt[k + 1][h], w2_ = Wt[k + 2][h], w3_ = Wt[k + 3][h];
        #pragma unroll
        for (int bb = 0; bb < 16; ++bb) {
            float4 hv = *(const float4*)&Ht[bg * 16 + bb][k];
            acc[bb] += hv.x * w0_ + hv.y * w1_ + hv.z * w2_ + hv.w * w3_;
        }
    }
    #pragma unroll
    for (int bb = 0; bb < 16; ++bb) {
        int b = bg * 16 + bb;
        z1part[(kc * 64 + b) * 1024 + hc * 64 + h] = acc[bb];
    }
}

// KE: out[b] = sum_h relu(b1[h] + sum_kc z1part[kc][b][h]) * Wo[h] + bo
__global__ __launch_bounds__(256) void kE(const float* __restrict__ z1part,
                                          const float* __restrict__ b1,
                                          const float* __restrict__ Wo,
                                          const float* __restrict__ bo,
                                          float* __restrict__ out) {
    int b = blockIdx.x;
    int tid = threadIdx.x;
    float acc = 0.f;
    #pragma unroll
    for (int i = 0; i < 4; ++i) {
        int h = tid + i * 256;
        float z = b1[h];
        #pragma unroll
        for (int kc = 0; kc < 16; ++kc) z += z1part[(kc * 64 + b) * 1024 + h];
        acc += fmaxf(z, 0.f) * Wo[h];
    }
    #pragma unroll
    for (int off = 32; off >= 1; off >>= 1) acc += __shfl_down(acc, off);
    __shared__ float red[4];
    if ((tid & 63) == 0) red[tid >> 6] = acc;
    __syncthreads();
    if (tid == 0) out[b] = red[0] + red[1] + red[2] + red[3] + bo[0];
}

extern "C" void kernel_launch(void* const* d_in, const int* in_sizes, int n_in,
                              void* d_out, int out_size, void* d_ws, size_t ws_size,
                              hipStream_t stream) {
    const int*   x     = (const int*)d_in[0];    // (64,128) 0/1
    const int*   masks = (const int*)d_in[1];    // (3,128) 0/1
    const float* W0    = (const float*)d_in[2];  // (8256,1024)
    const float* b0    = (const float*)d_in[3];  // (1024)
    const float* W1    = (const float*)d_in[4];  // (1024,1024)
    const float* b1    = (const float*)d_in[5];  // (1024)
    const float* Wo    = (const float*)d_in[6];  // (1024,1)
    const float* bo    = (const float*)d_in[7];  // (1)
    float* out = (float*)d_out;                  // (64,1)

    char* ws = (char*)d_ws;
    float* S      = (float*)(ws);                      // 64*128*4      = 32 KB
    float* A2     = (float*)(ws + (32u   << 10));      // 192*1024*4    = 768 KB
    float* G2     = (float*)(ws + (800u  << 10));      // 192*1024*4    = 768 KB
    float* h0     = (float*)(ws + (1568u << 10));      // 64*1024*4     = 256 KB
    float* z1part = (float*)(ws + (1824u << 10));      // 16*64*1024*4  = 4 MB

    kB<<<769, 256, 0, stream>>>(x, masks, W0, S, A2, G2);
    kC<<<dim3(16, 4), 256, 0, stream>>>(A2, G2, S, b0, h0);
    kD<<<dim3(16, 16), 256, 0, stream>>>(h0, W1, z1part);
    kE<<<64, 256, 0, stream>>>(z1part, b1, Wo, bo, out);
}

// Round 7
// 36.196 us; speedup vs baseline: 1.7129x; 1.3953x over previous
//
#include <hip/hip_runtime.h>
#include <cstdint>

#define DEVFN __device__ __forceinline__

struct U128 { unsigned long long lo, hi; };

// rotate right by s (1..127): bit q of result = bit (q+s)%128 of w
DEVFN U128 rotr128(U128 w, int s) {
    U128 r;
    if (s == 64) { r.lo = w.hi; r.hi = w.lo; return r; }
    if (s < 64) {
        r.lo = (w.lo >> s) | (w.hi << (64 - s));
        r.hi = (w.hi >> s) | (w.lo << (64 - s));
    } else {
        int t = s - 64;
        unsigned long long lo = w.hi, hi = w.lo;
        r.lo = (lo >> t) | (hi << (64 - t));
        r.hi = (hi >> t) | (lo << (64 - t));
    }
    return r;
}

// logical shift right by s (1..127)
DEVFN U128 shr128(U128 w, int s) {
    U128 r;
    if (s == 64) { r.lo = w.hi; r.hi = 0ull; return r; }
    if (s < 64) {
        r.lo = (w.lo >> s) | (w.hi << (64 - s));
        r.hi = w.hi >> s;
    } else {
        r.lo = w.hi >> (s - 64); r.hi = 0ull;
    }
    return r;
}

// KB: fused {S computation (block 768)} + {balanced W0 reduction (blocks 0..767)}
// (byte-identical to the 39 µs round-2 kernel)
__global__ __launch_bounds__(256) void kB(const int* __restrict__ x,
                                          const int* __restrict__ masks,
                                          const float* __restrict__ W0,
                                          float* __restrict__ S,
                                          float* __restrict__ A2,
                                          float* __restrict__ G2) {
    int bid = blockIdx.x;
    int tid = threadIdx.x;

    if (bid == 768) {
        int b = tid >> 2;        // 64 rows of x
        int rc = tid & 3;        // 4 chunks of 32 r's
        const int* xb = x + b * 128;
        U128 w; w.lo = 0ull; w.hi = 0ull;
        #pragma unroll
        for (int p = 0; p < 64; ++p) w.lo |= (unsigned long long)(xb[p] & 1) << p;
        #pragma unroll
        for (int p = 0; p < 64; ++p) w.hi |= (unsigned long long)(xb[64 + p] & 1) << p;
        int r0 = rc * 32;
        if (r0 & 32) { U128 t = rotr128(w, 32); w.lo ^= t.lo; w.hi ^= t.hi; }
        if (r0 & 64) { U128 t = rotr128(w, 64); w.lo ^= t.lo; w.hi ^= t.hi; }
        for (int rr = 0; rr < 32; ++rr) {
            int r = r0 + rr;
            int pc = __popcll(w.lo) + __popcll(w.hi);
            int sv = (r == 0) ? pc : (128 - pc);
            S[b * 128 + r] = (float)(2 * sv);
            U128 t = rotr128(w, 1);
            w.lo ^= t.lo; w.hi ^= t.hi;
        }
        return;
    }

    int hc = bid & 3;            // 4 chunks of 256 h
    int y  = bid >> 2;           // 0..191 (r, segment) task
    int r, jstart, jend, slice;
    if (y < 128) { r = y >> 1; slice = y & 1; jstart = slice * 64; jend = (slice == 0) ? 64 : (128 - r); }
    else         { r = y - 64;  slice = 0;    jstart = 0;          jend = 128 - r; }

    int h = hc * 256 + tid;

    __shared__ unsigned long long mw[3][2];
    __shared__ float cA[64], cG[64];

    if (tid < 128) {
        int half = tid >> 6;
        int lane = tid & 63;
        #pragma unroll
        for (int k = 0; k < 3; ++k) {
            unsigned long long bal = __ballot(masks[k * 128 + half * 64 + lane] & 1);
            if (lane == 0) mw[k][half] = bal;
        }
    }
    __syncthreads();
    if (tid < 64) {
        int j = jstart + tid;
        int c = 0;
        #pragma unroll
        for (int k = 0; k < 3; ++k) {
            U128 m; m.lo = mw[k][0]; m.hi = mw[k][1];
            #pragma unroll
            for (int s = 1; s <= 64; s <<= 1) {
                if (r & s) { U128 t = shr128(m, s); m.lo ^= t.lo; m.hi ^= t.hi; }
            }
            int bit = (j < 64) ? (int)((m.lo >> j) & 1) : (int)((m.hi >> (j - 64)) & 1);
            c += bit;
        }
        cA[tid] = 0.5f * (float)c - 1.0f;
        cG[tid] = (float)(2 - c) * (1.0f / 256.0f);
    }
    __syncthreads();

    int off = r * 128 - (r * (r - 1)) / 2;
    const float* p = W0 + (off + jstart) * 1024 + h;
    int L = jend - jstart;
    float accA = 0.f, accG = 0.f;
    #pragma unroll 8
    for (int j = 0; j < L; ++j) {
        float w = p[j * 1024];
        accA += cA[j] * w;
        accG += cG[j] * w;
    }
    int row = slice * 128 + r;
    A2[row * 1024 + h] = accA;
    G2[row * 1024 + h] = accG;
}

// kF: fused layer-1 + layer-2 split-K.
// grid (hc 8, kc 16, bs 4) = 512 blocks, 256 threads.
// Phase A: h0tile[b 16][k 64] = relu(b0 + sum_row A2[row][k] + S[b][row&127]*G2[row][k])
// Phase B: z1part[kc][b][hc*128..+127] = h0tile . W1tile
__global__ __launch_bounds__(256) void kF(const float* __restrict__ A2,
                                          const float* __restrict__ G2,
                                          const float* __restrict__ S,
                                          const float* __restrict__ b0,
                                          const float* __restrict__ W1,
                                          float* __restrict__ z1part) {
    int hc = blockIdx.x;          // 0..7   (128 h-cols each)
    int kc = blockIdx.y;          // 0..15  (64 k each)
    int bs = blockIdx.z;          // 0..3   (16 b each)
    int tid = threadIdx.x;

    __shared__ float W1sh[64][128];   // 32 KB
    __shared__ float Ssh[16][128];    // 8 KB
    __shared__ float h0sh[16][64];    // 4 KB

    // stage W1 tile early (HBM read overlaps phase A compute)
    #pragma unroll
    for (int t = 0; t < 32; ++t) {
        int idx = tid + t * 256;      // 0..8191
        int kk = idx >> 7, hcl = idx & 127;
        W1sh[kk][hcl] = W1[(kc * 64 + kk) * 1024 + hc * 128 + hcl];
    }
    // stage S rows for this b-tile
    #pragma unroll
    for (int t = 0; t < 8; ++t) {
        int idx = tid + t * 256;      // 0..2047
        int bl = idx >> 7, r = idx & 127;
        Ssh[bl][r] = S[(bs * 16 + bl) * 128 + r];
    }
    __syncthreads();

    // ---- Phase A: compute h0 sub-tile ----
    {
        int k = tid & 63;             // k-lane
        int bg = tid >> 6;            // 0..3, 4 b each
        const float* a2p = A2 + kc * 64 + k;
        const float* g2p = G2 + kc * 64 + k;
        float accA = 0.f;
        float acc[4] = {0.f, 0.f, 0.f, 0.f};
        #pragma unroll 8
        for (int row = 0; row < 192; ++row) {
            float a = a2p[row * 1024];
            float g = g2p[row * 1024];
            accA += a;
            int r = row & 127;
            #pragma unroll
            for (int bb = 0; bb < 4; ++bb)
                acc[bb] += Ssh[bg * 4 + bb][r] * g;   // wave-uniform broadcast
        }
        float base = b0[kc * 64 + k] + accA;
        #pragma unroll
        for (int bb = 0; bb < 4; ++bb)
            h0sh[bg * 4 + bb][k] = fmaxf(base + acc[bb], 0.f);
    }
    __syncthreads();

    // ---- Phase B: z1part tile = h0sh (16x64) . W1sh (64x128) ----
    {
        int hcol = tid & 127;         // h-lane
        int bg2 = tid >> 7;           // 0..1, 8 b each
        float acc2[8];
        #pragma unroll
        for (int i = 0; i < 8; ++i) acc2[i] = 0.f;
        #pragma unroll 4
        for (int kk = 0; kk < 64; ++kk) {
            float w = W1sh[kk][hcol];
            #pragma unroll
            for (int bb = 0; bb < 8; ++bb)
                acc2[bb] += h0sh[bg2 * 8 + bb][kk] * w;   // broadcast
        }
        #pragma unroll
        for (int bb = 0; bb < 8; ++bb) {
            int b = bs * 16 + bg2 * 8 + bb;
            z1part[(kc * 64 + b) * 1024 + hc * 128 + hcol] = acc2[bb];
        }
    }
}

// kE: out[b] = sum_h relu(b1[h] + sum_kc z1part[kc][b][h]) * Wo[h] + bo
// 1024 threads (16 waves) per block to hide the strided z1part reads.
__global__ __launch_bounds__(1024) void kE(const float* __restrict__ z1part,
                                           const float* __restrict__ b1,
                                           const float* __restrict__ Wo,
                                           const float* __restrict__ bo,
                                           float* __restrict__ out) {
    int b = blockIdx.x;
    int h = threadIdx.x;
    float z = b1[h];
    #pragma unroll
    for (int kc = 0; kc < 16; ++kc) z += z1part[(kc * 64 + b) * 1024 + h];
    float acc = fmaxf(z, 0.f) * Wo[h];
    #pragma unroll
    for (int off = 32; off >= 1; off >>= 1) acc += __shfl_down(acc, off);
    __shared__ float red[16];
    if ((h & 63) == 0) red[h >> 6] = acc;
    __syncthreads();
    if (h == 0) {
        float s = bo[0];
        #pragma unroll
        for (int i = 0; i < 16; ++i) s += red[i];
        out[b] = s;
    }
}

extern "C" void kernel_launch(void* const* d_in, const int* in_sizes, int n_in,
                              void* d_out, int out_size, void* d_ws, size_t ws_size,
                              hipStream_t stream) {
    const int*   x     = (const int*)d_in[0];    // (64,128) 0/1
    const int*   masks = (const int*)d_in[1];    // (3,128) 0/1
    const float* W0    = (const float*)d_in[2];  // (8256,1024)
    const float* b0    = (const float*)d_in[3];  // (1024)
    const float* W1    = (const float*)d_in[4];  // (1024,1024)
    const float* b1    = (const float*)d_in[5];  // (1024)
    const float* Wo    = (const float*)d_in[6];  // (1024,1)
    const float* bo    = (const float*)d_in[7];  // (1)
    float* out = (float*)d_out;                  // (64,1)

    char* ws = (char*)d_ws;
    float* S      = (float*)(ws);                      // 64*128*4      = 32 KB
    float* A2     = (float*)(ws + (32u   << 10));      // 192*1024*4    = 768 KB
    float* G2     = (float*)(ws + (800u  << 10));      // 192*1024*4    = 768 KB
    float* z1part = (float*)(ws + (1568u << 10));      // 16*64*1024*4  = 4 MB

    kB<<<769, 256, 0, stream>>>(x, masks, W0, S, A2, G2);
    kF<<<dim3(8, 16, 4), 256, 0, stream>>>(A2, G2, S, b0, W1, z1part);
    kE<<<64, 1024, 0, stream>>>(z1part, b1, Wo, bo, out);
}